// Round 1
// baseline (102.932 us; speedup 1.0000x reference)
//
#include <hip/hip_runtime.h>
#include <hip/hip_bf16.h>

// Problem constants (from reference)
#define EMB   128
#define SEQ   200

// Kernel 1: p[v][o] = sum_k embeddings[v][k] * W[o][k]   (o = 0,1)
// One wave (64 lanes) per vocab row; each lane handles 2 consecutive floats
// (float2 -> 8 B/lane -> 512 B coalesced per wave-row read).
__global__ __launch_bounds__(256) void project_vocab_kernel(
    const float* __restrict__ emb,   // [VOCAB, 128]
    const float* __restrict__ W,     // [2, 128]
    float*       __restrict__ p,     // [VOCAB, 2]
    int vocab)
{
    int gid  = blockIdx.x * blockDim.x + threadIdx.x;
    int row  = gid >> 6;
    int lane = threadIdx.x & 63;
    if (row >= vocab) return;

    const float2 e  = ((const float2*)(emb + (size_t)row * EMB))[lane];
    const float2 w0 = ((const float2*)(W))[lane];         // W[0][2l..2l+1]
    const float2 w1 = ((const float2*)(W + EMB))[lane];   // W[1][2l..2l+1]

    float p0 = e.x * w0.x + e.y * w0.y;
    float p1 = e.x * w1.x + e.y * w1.y;

    // butterfly reduce across the 64-lane wave
    #pragma unroll
    for (int off = 32; off > 0; off >>= 1) {
        p0 += __shfl_xor(p0, off);
        p1 += __shfl_xor(p1, off);
    }

    if (lane == 0) {
        ((float2*)p)[row] = make_float2(p0, p1);
    }
}

// Kernel 2: per batch row, masked mean of p[x[b,s]] over s, + bias.
// One wave per batch row. x reads are coalesced (lane s-offsets); p gathers
// hit an 800 KB L2-resident table.
__global__ __launch_bounds__(256) void pool_rows_kernel(
    const int*   __restrict__ x,     // [B, SEQ] (int32, -1 = pad)
    const float* __restrict__ p,     // [VOCAB, 2]
    const float* __restrict__ bias,  // [2]
    float*       __restrict__ out,   // [B, 2]
    int B)
{
    int gid  = blockIdx.x * blockDim.x + threadIdx.x;
    int row  = gid >> 6;
    int lane = threadIdx.x & 63;
    if (row >= B) return;

    const int* xr = x + (size_t)row * SEQ;
    float s0 = 0.f, s1 = 0.f;
    int cnt = 0;

    // SEQ = 200 = 3*64 + 8
    #pragma unroll
    for (int it = 0; it < 4; ++it) {
        int s = lane + it * 64;
        if (s < SEQ) {
            int idx = xr[s];
            if (idx >= 0) {
                float2 pv = ((const float2*)p)[idx];
                s0 += pv.x;
                s1 += pv.y;
                cnt += 1;
            }
        }
    }

    #pragma unroll
    for (int off = 32; off > 0; off >>= 1) {
        s0  += __shfl_xor(s0, off);
        s1  += __shfl_xor(s1, off);
        cnt += __shfl_xor(cnt, off);
    }

    if (lane == 0) {
        float inv = 1.0f / (float)cnt;   // cnt >= 1 (col 0 always valid)
        float b0 = bias[0], b1 = bias[1];
        ((float2*)out)[row] = make_float2(s0 * inv + b0, s1 * inv + b1);
    }
}

extern "C" void kernel_launch(void* const* d_in, const int* in_sizes, int n_in,
                              void* d_out, int out_size, void* d_ws, size_t ws_size,
                              hipStream_t stream) {
    const int*   x    = (const int*)d_in[0];    // [B, SEQ] int32
    const float* emb  = (const float*)d_in[1];  // [VOCAB, EMB]
    const float* W    = (const float*)d_in[2];  // [2, EMB]
    const float* bias = (const float*)d_in[3];  // [2]
    float* out = (float*)d_out;                 // [B, 2]

    const int vocab = in_sizes[1] / EMB;        // 100000
    const int B     = in_sizes[0] / SEQ;        // 4096

    float* p = (float*)d_ws;                    // [VOCAB, 2] = 800 KB scratch

    {
        int waves  = vocab;
        int threads = 256;
        int blocks  = (waves * 64 + threads - 1) / threads;
        project_vocab_kernel<<<blocks, threads, 0, stream>>>(emb, W, p, vocab);
    }
    {
        int waves  = B;
        int threads = 256;
        int blocks  = (waves * 64 + threads - 1) / threads;
        pool_rows_kernel<<<blocks, threads, 0, stream>>>(x, p, bias, out, B);
    }
}

// Round 2
// 94.740 us; speedup vs baseline: 1.0865x; 1.0865x over previous
//
#include <hip/hip_runtime.h>
#include <hip/hip_bf16.h>

#define EMB   128
#define SEQ   200

// Kernel 1: p[v][o] = dot(embeddings[v], W[o])  for o=0,1.
// 2 rows per wave: lanes 0-31 -> row 2w, lanes 32-63 -> row 2w+1.
// Each lane loads float4 (16 B) => 1 KiB coalesced per wave-instruction.
// Butterfly reduce within each 32-lane half (xor offsets < 32 stay in-half).
__global__ __launch_bounds__(256) void project_vocab_kernel(
    const float* __restrict__ emb,   // [VOCAB, 128]
    const float* __restrict__ W,     // [2, 128]
    float*       __restrict__ p,     // [VOCAB, 2]
    int vocab)
{
    int gid  = blockIdx.x * blockDim.x + threadIdx.x;
    int wave = gid >> 6;
    int lane = threadIdx.x & 63;
    int half = lane >> 5;            // 0 or 1
    int hl   = lane & 31;            // lane within half
    int row  = wave * 2 + half;
    if (row >= vocab) return;

    const float4 e  = ((const float4*)(emb + (size_t)row * EMB))[hl];
    const float4 w0 = ((const float4*)(W))[hl];          // W[0][4hl..4hl+3]
    const float4 w1 = ((const float4*)(W + EMB))[hl];    // W[1][...]

    float p0 = e.x * w0.x + e.y * w0.y + e.z * w0.z + e.w * w0.w;
    float p1 = e.x * w1.x + e.y * w1.y + e.z * w1.z + e.w * w1.w;

    #pragma unroll
    for (int off = 16; off > 0; off >>= 1) {
        p0 += __shfl_xor(p0, off);   // off < 32: stays within the 32-lane half
        p1 += __shfl_xor(p1, off);
    }

    if (hl == 0) {
        ((float2*)p)[row] = make_float2(p0, p1);
    }
}

// Kernel 2: per batch row, masked mean of p[x[b,s]] over s, then + bias.
// One wave per batch row. x loaded as int4: SEQ=200 => 50 int4, lanes 0-49.
__global__ __launch_bounds__(256) void pool_rows_kernel(
    const int*   __restrict__ x,     // [B, SEQ] (int32, -1 = pad)
    const float* __restrict__ p,     // [VOCAB, 2]
    const float* __restrict__ bias,  // [2]
    float*       __restrict__ out,   // [B, 2]
    int B)
{
    int gid  = blockIdx.x * blockDim.x + threadIdx.x;
    int row  = gid >> 6;
    int lane = threadIdx.x & 63;
    if (row >= B) return;

    const int* xr = x + (size_t)row * SEQ;
    float s0 = 0.f, s1 = 0.f;
    int cnt = 0;

    if (lane < SEQ / 4) {            // 50 active lanes
        int4 v = ((const int4*)xr)[lane];
        int ids[4] = { v.x, v.y, v.z, v.w };
        #pragma unroll
        for (int j = 0; j < 4; ++j) {
            if (ids[j] >= 0) {
                float2 pv = ((const float2*)p)[ids[j]];
                s0 += pv.x;
                s1 += pv.y;
                cnt += 1;
            }
        }
    }

    #pragma unroll
    for (int off = 32; off > 0; off >>= 1) {
        s0  += __shfl_xor(s0, off);
        s1  += __shfl_xor(s1, off);
        cnt += __shfl_xor(cnt, off);
    }

    if (lane == 0) {
        float inv = 1.0f / (float)cnt;   // cnt >= 1 (col 0 always valid)
        ((float2*)out)[row] = make_float2(s0 * inv + bias[0], s1 * inv + bias[1]);
    }
}

extern "C" void kernel_launch(void* const* d_in, const int* in_sizes, int n_in,
                              void* d_out, int out_size, void* d_ws, size_t ws_size,
                              hipStream_t stream) {
    const int*   x    = (const int*)d_in[0];    // [B, SEQ] int32
    const float* emb  = (const float*)d_in[1];  // [VOCAB, EMB]
    const float* W    = (const float*)d_in[2];  // [2, EMB]
    const float* bias = (const float*)d_in[3];  // [2]
    float* out = (float*)d_out;                 // [B, 2]

    const int vocab = in_sizes[1] / EMB;        // 100000
    const int B     = in_sizes[0] / SEQ;        // 4096

    float* p = (float*)d_ws;                    // [VOCAB, 2] = 800 KB scratch

    {
        int waves   = (vocab + 1) / 2;          // 2 rows per wave
        int threads = 256;
        int blocks  = (waves * 64 + threads - 1) / threads;
        project_vocab_kernel<<<blocks, threads, 0, stream>>>(emb, W, p, vocab);
    }
    {
        int waves   = B;
        int threads = 256;
        int blocks  = (waves * 64 + threads - 1) / threads;
        pool_rows_kernel<<<blocks, threads, 0, stream>>>(x, p, bias, out, B);
    }
}